// Round 7
// baseline (193.940 us; speedup 1.0000x reference)
//
#include <hip/hip_runtime.h>
#include <cstdint>

#define N_NODES 50000
#define N_EDGES 800000
#define N_PAIRS 200000
#define IN_DIM 128
#define HID 64
#define N_WAVES_GEMM (N_NODES / 16)           // 3125
#define NBIN 196                              // high-byte bins (node space / 256)
#define NCH 320                               // edge chunks (decoupled from bins)
#define CHUNK ((N_EDGES + NCH - 1) / NCH)     // 2500
#define MB_GEMM ((N_WAVES_GEMM + 3) / 4)      // 782
#define NODE_BLOCKS ((N_NODES + 3) / 4)       // 12500
#define MEMBER_BLOCKS (N_PAIRS / 32)          // 6250 (32 pairs/block)

typedef __attribute__((ext_vector_type(8))) short bf16x8;
typedef __attribute__((ext_vector_type(4))) float f32x4;

__device__ __forceinline__ unsigned short bf16_rne(float f) {
    unsigned u = __float_as_uint(f);
    unsigned t = u + 0x7FFFu + ((u >> 16) & 1u);
    return (unsigned short)(t >> 16);
}
__device__ __forceinline__ void bf2f(unsigned u, float& a, float& b) {
    a = __uint_as_float(u << 16);
    b = __uint_as_float(u & 0xFFFF0000u);
}

// exclusive scan of the 256 per-bin totals -> exb[] (bins >= NBIN are zero)
__device__ __forceinline__ void scan_bins(const int* __restrict__ binCursor,
                                          int* sh, int* exb, int t)
{
    int v = binCursor[t];
    sh[t] = v; __syncthreads();
    #pragma unroll
    for (int off = 1; off < 256; off <<= 1) {
        int x = sh[t];
        int a = (t >= off) ? sh[t - off] : 0;
        __syncthreads();
        sh[t] = x + a;
        __syncthreads();
    }
    exb[t] = sh[t] - v;
    __syncthreads();
}

// ---- fused: per-chunk histogram + ticket reservation (blocks 0..NCH-1)
//      + W fragment prep (blocks NCH..NCH+31) ----
// Ticket: resv[b][bin] = atomicAdd(&binCursor[bin], cnt). After this launch
// binCursor[bin] == total count of bin. 256 hot-line atomics per block (NOT
// the per-edge random-RMW pattern — rounds 3/4 lesson).
__global__ __launch_bounds__(256) void hist_prep(
    const int* __restrict__ dst, int* __restrict__ binCursor, int* __restrict__ resv,
    const float* __restrict__ W1, const float* __restrict__ W2,
    unsigned short* __restrict__ w1hi, unsigned short* __restrict__ w1lo,
    unsigned short* __restrict__ w2hi, unsigned short* __restrict__ w2lo)
{
    const int t = threadIdx.x, b = blockIdx.x;
    if (b < NCH) {
        __shared__ int hist[256];
        hist[t] = 0; __syncthreads();
        const int beg = b * CHUNK, end = min(beg + CHUNK, N_EDGES);
        for (int e = beg + t; e < end; e += 256) atomicAdd(&hist[dst[e] >> 8], 1);
        __syncthreads();
        resv[b * 256 + t] = atomicAdd(&binCursor[t], hist[t]);
    } else {
        int tid = (b - NCH) * 256 + t;
        if (tid < 8192) {
            int jj = tid & 7, lane = (tid >> 3) & 63, tt = (tid >> 9) & 3, ks = tid >> 11;
            int k = ks * 32 + (lane >> 4) * 8 + jj;
            int n = tt * 16 + (lane & 15);
            float f = W1[k * HID + n];
            unsigned short hi = bf16_rne(f);
            float fhi = __uint_as_float(((unsigned)hi) << 16);
            w1hi[tid] = hi;
            w1lo[tid] = bf16_rne(f - fhi);
        }
        if (tid < 4096) {
            int jj = tid & 7, lane = (tid >> 3) & 63, tt = (tid >> 9) & 3, ks = tid >> 11;
            int k = ks * 32 + (lane >> 4) * 8 + jj;
            int n = tt * 16 + (lane & 15);
            float f = W2[k * HID + n];
            unsigned short hi = bf16_rne(f);
            float fhi = __uint_as_float(((unsigned)hi) << 16);
            w2hi[tid] = hi;
            w2lo[tid] = bf16_rne(f - fhi);
        }
    }
}

// layer-1 GEMM body: fp32 x, split-bf16 (hi*hi + hi*lo + lo*hi); z stored bf16.
// Conversion rides free in the scatter's shadow (round-5 lesson).
// 1-deep float4 prefetch breaks the serial load->convert->MFMA chain per ks
// while keeping VGPR low (scatter co-residents are latency-bound).
__device__ __forceinline__ void gemm1_body(
    int wave, int lane,
    const float* __restrict__ x,
    const unsigned short* __restrict__ whi, const unsigned short* __restrict__ wlo,
    const float* __restrict__ al, const float* __restrict__ ar,
    unsigned short* __restrict__ z, float* __restrict__ el, float* __restrict__ er)
{
    const int i0 = wave * 16;
    const int m = lane & 15, quad = lane >> 4;
    f32x4 acc[4] = {{0.f,0.f,0.f,0.f},{0.f,0.f,0.f,0.f},{0.f,0.f,0.f,0.f},{0.f,0.f,0.f,0.f}};
    const float* xrow = x + (size_t)(i0 + m) * IN_DIM;

    float4 c0 = *(const float4*)&xrow[quad * 8];
    float4 c1 = *(const float4*)&xrow[quad * 8 + 4];
    #pragma unroll 1
    for (int ks = 0; ks < 4; ++ks) {
        float4 n0, n1;
        if (ks < 3) {
            n0 = *(const float4*)&xrow[(ks + 1) * 32 + quad * 8];
            n1 = *(const float4*)&xrow[(ks + 1) * 32 + quad * 8 + 4];
        }
        float xs[8] = {c0.x, c0.y, c0.z, c0.w, c1.x, c1.y, c1.z, c1.w};
        bf16x8 ahi, alo;
        #pragma unroll
        for (int jj = 0; jj < 8; ++jj) {
            unsigned short hb = bf16_rne(xs[jj]);
            float fhi = __uint_as_float(((unsigned)hb) << 16);
            ahi[jj] = (short)hb;
            alo[jj] = (short)bf16_rne(xs[jj] - fhi);
        }
        #pragma unroll
        for (int t = 0; t < 4; ++t) {
            const bf16x8 bhi = *(const bf16x8*)&whi[(((ks * 4 + t) * 64) + lane) * 8];
            const bf16x8 blo = *(const bf16x8*)&wlo[(((ks * 4 + t) * 64) + lane) * 8];
            acc[t] = __builtin_amdgcn_mfma_f32_16x16x32_bf16(ahi, bhi, acc[t], 0, 0, 0);
            acc[t] = __builtin_amdgcn_mfma_f32_16x16x32_bf16(ahi, blo, acc[t], 0, 0, 0);
            acc[t] = __builtin_amdgcn_mfma_f32_16x16x32_bf16(alo, bhi, acc[t], 0, 0, 0);
        }
        c0 = n0; c1 = n1;
    }
    #pragma unroll
    for (int r = 0; r < 4; ++r) {
        const int row = quad * 4 + r;
        float se = 0.f, sr = 0.f;
        #pragma unroll
        for (int t = 0; t < 4; ++t) {
            float v = acc[t][r];
            z[(size_t)(i0 + row) * HID + t * 16 + m] = bf16_rne(v);
            se = fmaf(v, al[t * 16 + m], se);
            sr = fmaf(v, ar[t * 16 + m], sr);
        }
        #pragma unroll
        for (int off = 1; off < 16; off <<= 1) {
            se += __shfl_xor(se, off, 64);
            sr += __shfl_xor(sr, off, 64);
        }
        if (m == 0) { el[i0 + row] = se; er[i0 + row] = sr; }
    }
}

// fused: bucket scatter via tickets (blocks 0..NCH-1) + layer-1 GEMM (NCH..).
__global__ __launch_bounds__(256) void scatter_gemm1(
    const int* __restrict__ src, const int* __restrict__ dst,
    const int* __restrict__ binCursor, const int* __restrict__ resv,
    unsigned* __restrict__ pairs,
    const float* __restrict__ x,
    const unsigned short* __restrict__ whi, const unsigned short* __restrict__ wlo,
    const float* __restrict__ al, const float* __restrict__ ar,
    unsigned short* __restrict__ z, float* __restrict__ el, float* __restrict__ er)
{
    const int b = blockIdx.x;
    if (b < NCH) {
        __shared__ int sh[256], exb[256], base[256];
        const int t = threadIdx.y * 64 + threadIdx.x;
        scan_bins(binCursor, sh, exb, t);
        base[t] = exb[t] + resv[b * 256 + t];
        __syncthreads();
        const int beg = b * CHUNK, end = min(beg + CHUNK, N_EDGES);
        for (int e = beg + t; e < end; e += 256) {
            int s = src[e], d = dst[e];
            int pos = atomicAdd(&base[d >> 8], 1);
            pairs[pos] = ((unsigned)s << 16) | (unsigned)d;   // both ids < 2^16
        }
    } else {
        const int wave = (b - NCH) * 4 + threadIdx.y;
        if (wave < N_WAVES_GEMM)
            gemm1_body(wave, threadIdx.x, x, whi, wlo, al, ar, z, el, er);
    }
}

// ---- MSD pass 2: one block per 256-node segment -> row_start + csr_src (u16) ----
__global__ __launch_bounds__(256) void seg_sort(
    const unsigned* __restrict__ pairs, const int* __restrict__ binCursor,
    int* __restrict__ row_start, unsigned short* __restrict__ csr_src)
{
    __shared__ int sh[256], exb[256], hist[256], sc[256], offs[256];
    const int t = threadIdx.x, b = blockIdx.x;
    scan_bins(binCursor, sh, exb, t);
    const int segStart = exb[b];
    const int segEnd = (b < 255) ? exb[b + 1] : N_EDGES;   // exb[NBIN] == N_EDGES
    hist[t] = 0; __syncthreads();
    for (int i = segStart + t; i < segEnd; i += 256)
        atomicAdd(&hist[pairs[i] & 255], 1);
    __syncthreads();
    int v = hist[t]; sc[t] = v; __syncthreads();
    #pragma unroll
    for (int off = 1; off < 256; off <<= 1) {
        int x = sc[t];
        int a = (t >= off) ? sc[t - off] : 0;
        __syncthreads();
        sc[t] = x + a;
        __syncthreads();
    }
    const int excl = sc[t] - v;
    offs[t] = segStart + excl;
    const int node = b * 256 + t;
    if (node <= N_NODES) row_start[node] = segStart + excl;
    __syncthreads();
    for (int i = segStart + t; i < segEnd; i += 256) {
        unsigned p = pairs[i];
        int pos = atomicAdd(&offs[p & 255], 1);
        csr_src[pos] = (unsigned short)(p >> 16);
    }
}

// per-dst-node softmax-aggregate + relu body. One wave per node.
// LAST=false: writes bf16 h row (128B) to hdst (global OR LDS row pointer).
// LAST=true: writes head dots a_s,a_d only.
template <bool LAST>
__device__ __forceinline__ void agg_body(
    int i, int lane,
    const int* __restrict__ row_start, const unsigned short* __restrict__ csr_src,
    const float* __restrict__ el, const float* __restrict__ er,
    const unsigned short* __restrict__ z, unsigned short* __restrict__ hdst,
    const float* __restrict__ Wc, float* __restrict__ as, float* __restrict__ ad)
{
    const int rb = row_start[i], re = row_start[i + 1];
    const float er_i = er[i];
    const int es = lane >> 3;
    const int fl = lane & 7;

    float acc[8] = {0.f,0.f,0.f,0.f,0.f,0.f,0.f,0.f};
    float den = 0.f;

    int eA = rb + es;        bool vA = eA < re;
    int eB = eA + 8;         bool vB = eB < re;
    int sA = vA ? (int)csr_src[eA] : 0;
    int sB = vB ? (int)csr_src[eB] : 0;
    float elA = el[sA];
    uint4 zA = ((const uint4*)(z + (size_t)sA * HID))[fl];

    for (int e0 = rb; e0 < re; e0 += 8) {
        const int eC = e0 + 16 + es;
        const bool vC = eC < re;
        const int sC = vC ? (int)csr_src[eC] : 0;               // 2 ahead
        const float elB = el[sB];                                // 1 ahead
        const uint4 zB = ((const uint4*)(z + (size_t)sB * HID))[fl];

        float x = elA + er_i;
        float lr = x > 0.f ? x : 0.2f * x;
        float ex = vA ? __expf(lr) : 0.f;
        float z0, z1, z2, z3, z4, z5, z6, z7;
        bf2f(zA.x, z0, z1); bf2f(zA.y, z2, z3);
        bf2f(zA.z, z4, z5); bf2f(zA.w, z6, z7);
        acc[0] = fmaf(ex, z0, acc[0]); acc[1] = fmaf(ex, z1, acc[1]);
        acc[2] = fmaf(ex, z2, acc[2]); acc[3] = fmaf(ex, z3, acc[3]);
        acc[4] = fmaf(ex, z4, acc[4]); acc[5] = fmaf(ex, z5, acc[5]);
        acc[6] = fmaf(ex, z6, acc[6]); acc[7] = fmaf(ex, z7, acc[7]);
        den += ex;

        sA = sB; vA = vB; elA = elB; zA = zB;
        sB = sC; vB = vC;
    }
    #pragma unroll
    for (int off = 8; off < 64; off <<= 1) {
        #pragma unroll
        for (int q = 0; q < 8; ++q) acc[q] += __shfl_xor(acc[q], off, 64);
        den += __shfl_xor(den, off, 64);
    }
    if (es == 0) {
        float inv = 1.f / fmaxf(den, 1e-9f);
        float hv[8];
        #pragma unroll
        for (int q = 0; q < 8; ++q) hv[q] = fmaxf(acc[q] * inv, 0.f);
        if (LAST) {
            float ps = 0.f, pd = 0.f;
            #pragma unroll
            for (int q = 0; q < 8; ++q) {
                ps = fmaf(hv[q], Wc[fl * 8 + q], ps);
                pd = fmaf(hv[q], Wc[HID + fl * 8 + q], pd);
            }
            #pragma unroll
            for (int off = 1; off < 8; off <<= 1) {
                ps += __shfl_xor(ps, off, 64);
                pd += __shfl_xor(pd, off, 64);
            }
            if (fl == 0) { as[i] = ps; ad[i] = pd; }
        } else {
            unsigned short o[8];
            #pragma unroll
            for (int q = 0; q < 8; ++q) o[q] = bf16_rne(hv[q]);
            uint4 pk;
            pk.x = (unsigned)o[0] | ((unsigned)o[1] << 16);
            pk.y = (unsigned)o[2] | ((unsigned)o[3] << 16);
            pk.z = (unsigned)o[4] | ((unsigned)o[5] << 16);
            pk.w = (unsigned)o[6] | ((unsigned)o[7] << 16);
            ((uint4*)hdst)[fl] = pk;
        }
    }
}

// ---------------- fused layer-1 aggregate + layer-2 GEMM + membership --------
__global__ __launch_bounds__(256) void agg1_gemm2_member(
    const int* __restrict__ row_start, const unsigned short* __restrict__ csr_src,
    const float* __restrict__ el1, const float* __restrict__ er1,
    const unsigned short* __restrict__ z1,
    const unsigned short* __restrict__ whi, const unsigned short* __restrict__ wlo,
    const float* __restrict__ al, const float* __restrict__ ar,
    unsigned short* __restrict__ z2, float* __restrict__ el2, float* __restrict__ er2,
    const int* __restrict__ ps, const int* __restrict__ pd, int* __restrict__ found)
{
    const int b = blockIdx.x, lane = threadIdx.x, ty = threadIdx.y;
    if (b < N_WAVES_GEMM) {
        __shared__ __align__(16) unsigned short ht[16][72];   // 144B row stride
        const int i0 = b * 16;
        #pragma unroll 1
        for (int c = 0; c < 4; ++c) {
            const int r = ty * 4 + c;
            agg_body<false>(i0 + r, lane, row_start, csr_src, el1, er1, z1,
                            &ht[r][0], nullptr, nullptr, nullptr);
        }
        __syncthreads();
        if (ty == 0) {
            const int m = lane & 15, quad = lane >> 4;
            f32x4 acc[4] = {{0.f,0.f,0.f,0.f},{0.f,0.f,0.f,0.f},
                            {0.f,0.f,0.f,0.f},{0.f,0.f,0.f,0.f}};
            const unsigned short* xrow = &ht[m][0];
            #pragma unroll 1
            for (int ks = 0; ks < 2; ++ks) {
                const bf16x8 aa = *(const bf16x8*)&xrow[ks * 32 + quad * 8];
                #pragma unroll
                for (int tt = 0; tt < 4; ++tt) {
                    const bf16x8 bhi = *(const bf16x8*)&whi[(((ks * 4 + tt) * 64) + lane) * 8];
                    const bf16x8 blo = *(const bf16x8*)&wlo[(((ks * 4 + tt) * 64) + lane) * 8];
                    acc[tt] = __builtin_amdgcn_mfma_f32_16x16x32_bf16(aa, bhi, acc[tt], 0, 0, 0);
                    acc[tt] = __builtin_amdgcn_mfma_f32_16x16x32_bf16(aa, blo, acc[tt], 0, 0, 0);
                }
            }
            #pragma unroll
            for (int r = 0; r < 4; ++r) {
                const int row = quad * 4 + r;
                float se = 0.f, sr = 0.f;
                #pragma unroll
                for (int tt = 0; tt < 4; ++tt) {
                    float v = acc[tt][r];
                    z2[(size_t)(i0 + row) * HID + tt * 16 + m] = bf16_rne(v);
                    se = fmaf(v, al[tt * 16 + m], se);
                    sr = fmaf(v, ar[tt * 16 + m], sr);
                }
                #pragma unroll
                for (int off = 1; off < 16; off <<= 1) {
                    se += __shfl_xor(se, off, 64);
                    sr += __shfl_xor(sr, off, 64);
                }
                if (m == 0) { el2[i0 + row] = se; er2[i0 + row] = sr; }
            }
        }
    } else {
        const int r8 = lane & 7, g = lane >> 3;
        const int p = (b - N_WAVES_GEMM) * 32 + ty * 8 + g;
        const int s = ps[p], d = pd[p];
        const int rb = row_start[d], re = row_start[d + 1];
        int f = 0;
        for (int e = rb + r8; e < re; e += 8) f |= ((int)csr_src[e] == s) ? 1 : 0;
        #pragma unroll
        for (int off = 1; off < 8; off <<= 1) f |= __shfl_xor(f, off, 64);
        if (r8 == 0) found[p] = f;
    }
}

// layer-2 aggregate: writes a_s/a_d head dots only (no h).
__global__ __launch_bounds__(256) void agg2(
    const int* __restrict__ row_start, const unsigned short* __restrict__ csr_src,
    const float* __restrict__ el, const float* __restrict__ er,
    const unsigned short* __restrict__ z, const float* __restrict__ Wc,
    float* __restrict__ as, float* __restrict__ ad)
{
    const int i = blockIdx.x * 4 + threadIdx.y;
    if (i < N_NODES)
        agg_body<true>(i, threadIdx.x, row_start, csr_src, el, er, z,
                       nullptr, Wc, as, ad);
}

// final: out[p] = found ? sigmoid(a_s[s] + a_d[d] + bc) : 0
__global__ __launch_bounds__(256) void pair_tiny(
    const int* __restrict__ ps, const int* __restrict__ pd,
    const float* __restrict__ as, const float* __restrict__ ad,
    const float* __restrict__ bc, const int* __restrict__ found,
    float* __restrict__ out)
{
    const int p = blockIdx.x * 256 + threadIdx.x;
    if (p >= N_PAIRS) return;
    float v = as[ps[p]] + ad[pd[p]] + bc[0];
    float sg = 1.f / (1.f + __expf(-v));
    out[p] = found[p] ? sg : 0.f;
}

extern "C" void kernel_launch(void* const* d_in, const int* in_sizes, int n_in,
                              void* d_out, int out_size, void* d_ws, size_t ws_size,
                              hipStream_t stream)
{
    const float* feat = (const float*)d_in[0];
    const float* W1   = (const float*)d_in[1];
    const float* al1  = (const float*)d_in[2];
    const float* ar1  = (const float*)d_in[3];
    const float* W2   = (const float*)d_in[4];
    const float* al2  = (const float*)d_in[5];
    const float* ar2  = (const float*)d_in[6];
    const float* Wc   = (const float*)d_in[7];
    const float* bc   = (const float*)d_in[8];
    const int* src    = (const int*)d_in[9];
    const int* dst    = (const int*)d_in[10];
    const int* psrc   = (const int*)d_in[11];
    const int* pdst   = (const int*)d_in[12];
    float* out = (float*)d_out;

    char* ws = (char*)d_ws;
    unsigned short* z  = (unsigned short*)ws;  ws += (size_t)N_NODES * HID * 2;  // layer-1 z
    unsigned short* z2 = (unsigned short*)ws;  ws += (size_t)N_NODES * HID * 2;  // layer-2 z
    float* el = (float*)ws;               ws += (size_t)N_NODES * 4;
    float* er = (float*)ws;               ws += (size_t)N_NODES * 4;
    float* as = (float*)ws;               ws += (size_t)N_NODES * 4;
    float* ad = (float*)ws;               ws += (size_t)N_NODES * 4;
    float* el2 = (float*)ws;              ws += (size_t)N_NODES * 4;
    float* er2 = (float*)ws;              ws += (size_t)N_NODES * 4;
    int* row_start = (int*)ws;            ws += (size_t)(N_NODES + 1) * 4;
    int* binCursor = (int*)ws;            ws += 256 * 4;                     // zeroed
    int* resv = (int*)ws;                 ws += (size_t)NCH * 256 * 4;
    int* found = (int*)ws;                ws += (size_t)N_PAIRS * 4;
    ws = (char*)(((uintptr_t)ws + 255) & ~(uintptr_t)255);
    unsigned* pairs = (unsigned*)ws;      ws += (size_t)N_EDGES * 4;
    unsigned short* csr_src = (unsigned short*)ws;  ws += (size_t)N_EDGES * 2;
    ws = (char*)(((uintptr_t)ws + 255) & ~(uintptr_t)255);
    unsigned short* w1hi = (unsigned short*)ws;  ws += 8192 * 2;
    unsigned short* w1lo = (unsigned short*)ws;  ws += 8192 * 2;
    unsigned short* w2hi = (unsigned short*)ws;  ws += 4096 * 2;
    unsigned short* w2lo = (unsigned short*)ws;  ws += 4096 * 2;

    dim3 b64x4(64, 4);

    // 0) zero the 256 bin cursors (1 KB DMA node — replaces the scan1g kernel)
    hipMemsetAsync(binCursor, 0, 256 * sizeof(int), stream);
    // 1) per-chunk histogram + ticket reservation + W prep
    hist_prep<<<NCH + 32, 256, 0, stream>>>(dst, binCursor, resv,
        W1, W2, w1hi, w1lo, w2hi, w2lo);
    // 2) bucket scatter (tickets) || layer-1 GEMM (fused: gemm hides behind scatter)
    scatter_gemm1<<<NCH + MB_GEMM, b64x4, 0, stream>>>(src, dst, binCursor, resv,
        pairs, feat, w1hi, w1lo, al1, ar1, z, el, er);
    // 3) segment sort -> row_start + csr_src (u16)
    seg_sort<<<NBIN, 256, 0, stream>>>(pairs, binCursor, row_start, csr_src);
    // 4) layer-1 aggregate (LDS) + layer-2 GEMM || pair membership
    agg1_gemm2_member<<<N_WAVES_GEMM + MEMBER_BLOCKS, b64x4, 0, stream>>>(
        row_start, csr_src, el, er, z, w2hi, w2lo, al2, ar2,
        z2, el2, er2, psrc, pdst, found);
    // 5) layer-2 aggregate + head dots
    agg2<<<NODE_BLOCKS, b64x4, 0, stream>>>(row_start, csr_src, el2, er2, z2, Wc, as, ad);
    // 6) final pair output
    pair_tiny<<<(N_PAIRS + 255) / 256, 256, 0, stream>>>(psrc, pdst, as, ad, bc, found, out);
}

// Round 8
// 181.294 us; speedup vs baseline: 1.0698x; 1.0698x over previous
//
#include <hip/hip_runtime.h>
#include <cstdint>

#define N_NODES 50000
#define N_EDGES 800000
#define N_PAIRS 200000
#define IN_DIM 128
#define HID 64
#define N_WAVES_GEMM (N_NODES / 16)           // 3125
#define NBIN 196                              // high-byte bins (node space / 256)
#define NCH 320                               // edge chunks (decoupled from bins)
#define CHUNK ((N_EDGES + NCH - 1) / NCH)     // 2500
#define MHIST (NBIN * NCH)                    // 62720
#define SBG ((MHIST + 255) / 256)             // 245 scan blocks (fits 256-scan)
#define MB_GEMM ((N_WAVES_GEMM + 3) / 4)      // 782
#define NODE_BLOCKS ((N_NODES + 3) / 4)       // 12500
#define MEMBER_BLOCKS (N_PAIRS / 32)          // 6250 (32 pairs/block)
#define SEG_T 1024                            // seg_sort block width

typedef __attribute__((ext_vector_type(8))) short bf16x8;
typedef __attribute__((ext_vector_type(4))) float f32x4;

__device__ __forceinline__ unsigned short bf16_rne(float f) {
    unsigned u = __float_as_uint(f);
    unsigned t = u + 0x7FFFu + ((u >> 16) & 1u);
    return (unsigned short)(t >> 16);
}
__device__ __forceinline__ void bf2f(unsigned u, float& a, float& b) {
    a = __uint_as_float(u << 16);
    b = __uint_as_float(u & 0xFFFF0000u);
}

// ---- fused: MSD pass-1 histogram (blocks 0..319) + W fragment prep ----
__global__ __launch_bounds__(256) void hist_prep(
    const int* __restrict__ dst, int* __restrict__ histHi,
    const float* __restrict__ W1, const float* __restrict__ W2,
    unsigned short* __restrict__ w1hi, unsigned short* __restrict__ w1lo,
    unsigned short* __restrict__ w2hi, unsigned short* __restrict__ w2lo)
{
    const int t = threadIdx.x, b = blockIdx.x;
    if (b < NCH) {
        __shared__ int hist[256];
        hist[t] = 0; __syncthreads();
        const int beg = b * CHUNK, end = min(beg + CHUNK, N_EDGES);
        for (int e = beg + t; e < end; e += 256) atomicAdd(&hist[dst[e] >> 8], 1);
        __syncthreads();
        if (t < NBIN) histHi[t * NCH + b] = hist[t];
    } else {
        int tid = (b - NCH) * 256 + t;
        if (tid < 8192) {
            int jj = tid & 7, lane = (tid >> 3) & 63, tt = (tid >> 9) & 3, ks = tid >> 11;
            int k = ks * 32 + (lane >> 4) * 8 + jj;
            int n = tt * 16 + (lane & 15);
            float f = W1[k * HID + n];
            unsigned short hi = bf16_rne(f);
            float fhi = __uint_as_float(((unsigned)hi) << 16);
            w1hi[tid] = hi;
            w1lo[tid] = bf16_rne(f - fhi);
        }
        if (tid < 4096) {
            int jj = tid & 7, lane = (tid >> 3) & 63, tt = (tid >> 9) & 3, ks = tid >> 11;
            int k = ks * 32 + (lane >> 4) * 8 + jj;
            int n = tt * 16 + (lane & 15);
            float f = W2[k * HID + n];
            unsigned short hi = bf16_rne(f);
            float fhi = __uint_as_float(((unsigned)hi) << 16);
            w2hi[tid] = hi;
            w2lo[tid] = bf16_rne(f - fhi);
        }
    }
}

// device-wide scan step 1 (standalone, tiny)
__global__ __launch_bounds__(256) void scan1g(
    int* __restrict__ histHi, int* __restrict__ bsums)
{
    __shared__ int sh[256];
    const int t = threadIdx.x;
    const int i = blockIdx.x * 256 + t;
    int v = (i < MHIST) ? histHi[i] : 0;
    sh[t] = v; __syncthreads();
    #pragma unroll
    for (int off = 1; off < 256; off <<= 1) {
        int x = sh[t];
        int a = (t >= off) ? sh[t - off] : 0;
        __syncthreads();
        sh[t] = x + a;
        __syncthreads();
    }
    if (i < MHIST) histHi[i] = sh[t] - v;
    if (t == 255) bsums[blockIdx.x] = sh[255];
}

// in-block exclusive scan of the SBG (245) bsums partials -> exb[] (256 threads)
__device__ __forceinline__ void scan_bsums(const int* __restrict__ bsums,
                                           int* sh, int* exb, int t)
{
    int v = (t < SBG) ? bsums[t] : 0;
    sh[t] = v; __syncthreads();
    #pragma unroll
    for (int off = 1; off < 256; off <<= 1) {
        int x = sh[t];
        int a = (t >= off) ? sh[t - off] : 0;
        __syncthreads();
        sh[t] = x + a;
        __syncthreads();
    }
    exb[t] = sh[t] - v;
    __syncthreads();
}

// layer-1 GEMM body: fp32 x, split-bf16 (hi*hi + hi*lo + lo*hi); z stored bf16.
// (conversion rides free in the scatter's shadow — round-5 lesson)
__device__ __forceinline__ void gemm1_body(
    int wave, int lane,
    const float* __restrict__ x,
    const unsigned short* __restrict__ whi, const unsigned short* __restrict__ wlo,
    const float* __restrict__ al, const float* __restrict__ ar,
    unsigned short* __restrict__ z, float* __restrict__ el, float* __restrict__ er)
{
    const int i0 = wave * 16;
    const int m = lane & 15, quad = lane >> 4;
    f32x4 acc[4] = {{0.f,0.f,0.f,0.f},{0.f,0.f,0.f,0.f},{0.f,0.f,0.f,0.f},{0.f,0.f,0.f,0.f}};
    const float* xrow = x + (size_t)(i0 + m) * IN_DIM;

    #pragma unroll 1
    for (int ks = 0; ks < 4; ++ks) {
        const float4 xv0 = *(const float4*)&xrow[ks * 32 + quad * 8];
        const float4 xv1 = *(const float4*)&xrow[ks * 32 + quad * 8 + 4];
        float xs[8] = {xv0.x, xv0.y, xv0.z, xv0.w, xv1.x, xv1.y, xv1.z, xv1.w};
        bf16x8 ahi, alo;
        #pragma unroll
        for (int jj = 0; jj < 8; ++jj) {
            unsigned short hb = bf16_rne(xs[jj]);
            float fhi = __uint_as_float(((unsigned)hb) << 16);
            ahi[jj] = (short)hb;
            alo[jj] = (short)bf16_rne(xs[jj] - fhi);
        }
        #pragma unroll
        for (int t = 0; t < 4; ++t) {
            const bf16x8 bhi = *(const bf16x8*)&whi[(((ks * 4 + t) * 64) + lane) * 8];
            const bf16x8 blo = *(const bf16x8*)&wlo[(((ks * 4 + t) * 64) + lane) * 8];
            acc[t] = __builtin_amdgcn_mfma_f32_16x16x32_bf16(ahi, bhi, acc[t], 0, 0, 0);
            acc[t] = __builtin_amdgcn_mfma_f32_16x16x32_bf16(ahi, blo, acc[t], 0, 0, 0);
            acc[t] = __builtin_amdgcn_mfma_f32_16x16x32_bf16(alo, bhi, acc[t], 0, 0, 0);
        }
    }
    #pragma unroll
    for (int r = 0; r < 4; ++r) {
        const int row = quad * 4 + r;
        float se = 0.f, sr = 0.f;
        #pragma unroll
        for (int t = 0; t < 4; ++t) {
            float v = acc[t][r];
            z[(size_t)(i0 + row) * HID + t * 16 + m] = bf16_rne(v);
            se = fmaf(v, al[t * 16 + m], se);
            sr = fmaf(v, ar[t * 16 + m], sr);
        }
        #pragma unroll
        for (int off = 1; off < 16; off <<= 1) {
            se += __shfl_xor(se, off, 64);
            sr += __shfl_xor(sr, off, 64);
        }
        if (m == 0) { el[i0 + row] = se; er[i0 + row] = sr; }
    }
}

// fused: MSD pass-1 scatter (blocks 0..319) + layer-1 GEMM (blocks 320..).
__global__ __launch_bounds__(256) void scatter_gemm1(
    const int* __restrict__ src, const int* __restrict__ dst,
    const int* __restrict__ histEx, const int* __restrict__ bsums,
    unsigned* __restrict__ pairs,
    const float* __restrict__ x,
    const unsigned short* __restrict__ whi, const unsigned short* __restrict__ wlo,
    const float* __restrict__ al, const float* __restrict__ ar,
    unsigned short* __restrict__ z, float* __restrict__ el, float* __restrict__ er)
{
    const int b = blockIdx.x;
    if (b < NCH) {
        __shared__ int sh[256], exb[256], base[256];
        const int t = threadIdx.y * 64 + threadIdx.x;
        scan_bsums(bsums, sh, exb, t);
        if (t < NBIN) {
            int idx = t * NCH + b;
            base[t] = histEx[idx] + exb[idx >> 8];
        }
        __syncthreads();
        const int beg = b * CHUNK, end = min(beg + CHUNK, N_EDGES);
        for (int e = beg + t; e < end; e += 256) {
            int s = src[e], d = dst[e];
            int pos = atomicAdd(&base[d >> 8], 1);
            pairs[pos] = ((unsigned)s << 16) | (unsigned)d;   // both ids < 2^16
        }
    } else {
        const int wave = (b - NCH) * 4 + threadIdx.y;
        if (wave < N_WAVES_GEMM)
            gemm1_body(wave, threadIdx.x, x, whi, wlo, al, ar, z, el, er);
    }
}

// ---- MSD pass 2: one block per 256-node segment -> row_start + csr_src (u16).
// 1024-thread blocks: 196 blocks are <1/CU (latency-bound), so 4x threads cut
// the per-pass strided iteration count 16->4. Scans stay 256-wide (t<256 does
// data work; all threads hit every barrier).
__global__ __launch_bounds__(SEG_T) void seg_sort(
    const unsigned* __restrict__ pairs, const int* __restrict__ histEx,
    const int* __restrict__ bsums,
    int* __restrict__ row_start, unsigned short* __restrict__ csr_src)
{
    __shared__ int sh[256], exb[256], hist[256], sc[256], offs[256];
    const int t = threadIdx.x, b = blockIdx.x;

    // wide scan_bsums: data work in t<256, barriers block-wide
    {
        int v = 0;
        if (t < 256) { v = (t < SBG) ? bsums[t] : 0; sh[t] = v; }
        __syncthreads();
        #pragma unroll
        for (int off = 1; off < 256; off <<= 1) {
            int x = 0, a = 0;
            if (t < 256) { x = sh[t]; a = (t >= off) ? sh[t - off] : 0; }
            __syncthreads();
            if (t < 256) sh[t] = x + a;
            __syncthreads();
        }
        if (t < 256) exb[t] = sh[t] - v;
        __syncthreads();
    }

    const int i0 = b * NCH;
    const int segStart = histEx[i0] + exb[i0 >> 8];
    int segEnd = N_EDGES;
    if (b < NBIN - 1) {
        const int i1 = (b + 1) * NCH;
        segEnd = histEx[i1] + exb[i1 >> 8];
    }

    if (t < 256) hist[t] = 0;
    __syncthreads();
    for (int i = segStart + t; i < segEnd; i += SEG_T)
        atomicAdd(&hist[pairs[i] & 255], 1);
    __syncthreads();

    // wide scan of hist -> exclusive offsets
    int v = 0;
    if (t < 256) { v = hist[t]; sc[t] = v; }
    __syncthreads();
    #pragma unroll
    for (int off = 1; off < 256; off <<= 1) {
        int x = 0, a = 0;
        if (t < 256) { x = sc[t]; a = (t >= off) ? sc[t - off] : 0; }
        __syncthreads();
        if (t < 256) sc[t] = x + a;
        __syncthreads();
    }
    if (t < 256) {
        const int excl = sc[t] - v;
        offs[t] = segStart + excl;
        const int node = b * 256 + t;
        if (node <= N_NODES) row_start[node] = segStart + excl;
    }
    __syncthreads();
    for (int i = segStart + t; i < segEnd; i += SEG_T) {
        unsigned p = pairs[i];
        int pos = atomicAdd(&offs[p & 255], 1);
        csr_src[pos] = (unsigned short)(p >> 16);
    }
}

// per-dst-node softmax-aggregate + relu body. One wave per node.
// LAST=false: writes bf16 h row (128B) to hdst (global OR LDS row pointer).
// LAST=true: writes head dots a_s,a_d only.
template <bool LAST>
__device__ __forceinline__ void agg_body(
    int i, int lane,
    const int* __restrict__ row_start, const unsigned short* __restrict__ csr_src,
    const float* __restrict__ el, const float* __restrict__ er,
    const unsigned short* __restrict__ z, unsigned short* __restrict__ hdst,
    const float* __restrict__ Wc, float* __restrict__ as, float* __restrict__ ad)
{
    const int rb = row_start[i], re = row_start[i + 1];
    const float er_i = er[i];
    const int es = lane >> 3;
    const int fl = lane & 7;

    float acc[8] = {0.f,0.f,0.f,0.f,0.f,0.f,0.f,0.f};
    float den = 0.f;

    int eA = rb + es;        bool vA = eA < re;
    int eB = eA + 8;         bool vB = eB < re;
    int sA = vA ? (int)csr_src[eA] : 0;
    int sB = vB ? (int)csr_src[eB] : 0;
    float elA = el[sA];
    uint4 zA = ((const uint4*)(z + (size_t)sA * HID))[fl];

    for (int e0 = rb; e0 < re; e0 += 8) {
        const int eC = e0 + 16 + es;
        const bool vC = eC < re;
        const int sC = vC ? (int)csr_src[eC] : 0;               // 2 ahead
        const float elB = el[sB];                                // 1 ahead
        const uint4 zB = ((const uint4*)(z + (size_t)sB * HID))[fl];

        float x = elA + er_i;
        float lr = x > 0.f ? x : 0.2f * x;
        float ex = vA ? __expf(lr) : 0.f;
        float z0, z1, z2, z3, z4, z5, z6, z7;
        bf2f(zA.x, z0, z1); bf2f(zA.y, z2, z3);
        bf2f(zA.z, z4, z5); bf2f(zA.w, z6, z7);
        acc[0] = fmaf(ex, z0, acc[0]); acc[1] = fmaf(ex, z1, acc[1]);
        acc[2] = fmaf(ex, z2, acc[2]); acc[3] = fmaf(ex, z3, acc[3]);
        acc[4] = fmaf(ex, z4, acc[4]); acc[5] = fmaf(ex, z5, acc[5]);
        acc[6] = fmaf(ex, z6, acc[6]); acc[7] = fmaf(ex, z7, acc[7]);
        den += ex;

        sA = sB; vA = vB; elA = elB; zA = zB;
        sB = sC; vB = vC;
    }
    #pragma unroll
    for (int off = 8; off < 64; off <<= 1) {
        #pragma unroll
        for (int q = 0; q < 8; ++q) acc[q] += __shfl_xor(acc[q], off, 64);
        den += __shfl_xor(den, off, 64);
    }
    if (es == 0) {
        float inv = 1.f / fmaxf(den, 1e-9f);
        float hv[8];
        #pragma unroll
        for (int q = 0; q < 8; ++q) hv[q] = fmaxf(acc[q] * inv, 0.f);
        if (LAST) {
            float ps = 0.f, pd = 0.f;
            #pragma unroll
            for (int q = 0; q < 8; ++q) {
                ps = fmaf(hv[q], Wc[fl * 8 + q], ps);
                pd = fmaf(hv[q], Wc[HID + fl * 8 + q], pd);
            }
            #pragma unroll
            for (int off = 1; off < 8; off <<= 1) {
                ps += __shfl_xor(ps, off, 64);
                pd += __shfl_xor(pd, off, 64);
            }
            if (fl == 0) { as[i] = ps; ad[i] = pd; }
        } else {
            unsigned short o[8];
            #pragma unroll
            for (int q = 0; q < 8; ++q) o[q] = bf16_rne(hv[q]);
            uint4 pk;
            pk.x = (unsigned)o[0] | ((unsigned)o[1] << 16);
            pk.y = (unsigned)o[2] | ((unsigned)o[3] << 16);
            pk.z = (unsigned)o[4] | ((unsigned)o[5] << 16);
            pk.w = (unsigned)o[6] | ((unsigned)o[7] << 16);
            ((uint4*)hdst)[fl] = pk;
        }
    }
}

// ---------------- fused layer-1 aggregate + layer-2 GEMM + membership --------
__global__ __launch_bounds__(256) void agg1_gemm2_member(
    const int* __restrict__ row_start, const unsigned short* __restrict__ csr_src,
    const float* __restrict__ el1, const float* __restrict__ er1,
    const unsigned short* __restrict__ z1,
    const unsigned short* __restrict__ whi, const unsigned short* __restrict__ wlo,
    const float* __restrict__ al, const float* __restrict__ ar,
    unsigned short* __restrict__ z2, float* __restrict__ el2, float* __restrict__ er2,
    const int* __restrict__ ps, const int* __restrict__ pd, int* __restrict__ found)
{
    const int b = blockIdx.x, lane = threadIdx.x, ty = threadIdx.y;
    if (b < N_WAVES_GEMM) {
        __shared__ __align__(16) unsigned short ht[16][72];   // 144B row stride
        const int i0 = b * 16;
        #pragma unroll 1
        for (int c = 0; c < 4; ++c) {
            const int r = ty * 4 + c;
            agg_body<false>(i0 + r, lane, row_start, csr_src, el1, er1, z1,
                            &ht[r][0], nullptr, nullptr, nullptr);
        }
        __syncthreads();
        if (ty == 0) {
            const int m = lane & 15, quad = lane >> 4;
            f32x4 acc[4] = {{0.f,0.f,0.f,0.f},{0.f,0.f,0.f,0.f},
                            {0.f,0.f,0.f,0.f},{0.f,0.f,0.f,0.f}};
            const unsigned short* xrow = &ht[m][0];
            #pragma unroll 1
            for (int ks = 0; ks < 2; ++ks) {
                const bf16x8 aa = *(const bf16x8*)&xrow[ks * 32 + quad * 8];
                #pragma unroll
                for (int tt = 0; tt < 4; ++tt) {
                    const bf16x8 bhi = *(const bf16x8*)&whi[(((ks * 4 + tt) * 64) + lane) * 8];
                    const bf16x8 blo = *(const bf16x8*)&wlo[(((ks * 4 + tt) * 64) + lane) * 8];
                    acc[tt] = __builtin_amdgcn_mfma_f32_16x16x32_bf16(aa, bhi, acc[tt], 0, 0, 0);
                    acc[tt] = __builtin_amdgcn_mfma_f32_16x16x32_bf16(aa, blo, acc[tt], 0, 0, 0);
                }
            }
            #pragma unroll
            for (int r = 0; r < 4; ++r) {
                const int row = quad * 4 + r;
                float se = 0.f, sr = 0.f;
                #pragma unroll
                for (int tt = 0; tt < 4; ++tt) {
                    float v = acc[tt][r];
                    z2[(size_t)(i0 + row) * HID + tt * 16 + m] = bf16_rne(v);
                    se = fmaf(v, al[tt * 16 + m], se);
                    sr = fmaf(v, ar[tt * 16 + m], sr);
                }
                #pragma unroll
                for (int off = 1; off < 16; off <<= 1) {
                    se += __shfl_xor(se, off, 64);
                    sr += __shfl_xor(sr, off, 64);
                }
                if (m == 0) { el2[i0 + row] = se; er2[i0 + row] = sr; }
            }
        }
    } else {
        const int r8 = lane & 7, g = lane >> 3;
        const int p = (b - N_WAVES_GEMM) * 32 + ty * 8 + g;
        const int s = ps[p], d = pd[p];
        const int rb = row_start[d], re = row_start[d + 1];
        int f = 0;
        for (int e = rb + r8; e < re; e += 8) f |= ((int)csr_src[e] == s) ? 1 : 0;
        #pragma unroll
        for (int off = 1; off < 8; off <<= 1) f |= __shfl_xor(f, off, 64);
        if (r8 == 0) found[p] = f;
    }
}

// layer-2 aggregate: writes a_s/a_d head dots only (no h).
__global__ __launch_bounds__(256) void agg2(
    const int* __restrict__ row_start, const unsigned short* __restrict__ csr_src,
    const float* __restrict__ el, const float* __restrict__ er,
    const unsigned short* __restrict__ z, const float* __restrict__ Wc,
    float* __restrict__ as, float* __restrict__ ad)
{
    const int i = blockIdx.x * 4 + threadIdx.y;
    if (i < N_NODES)
        agg_body<true>(i, threadIdx.x, row_start, csr_src, el, er, z,
                       nullptr, Wc, as, ad);
}

// final: out[p] = found ? sigmoid(a_s[s] + a_d[d] + bc) : 0
__global__ __launch_bounds__(256) void pair_tiny(
    const int* __restrict__ ps, const int* __restrict__ pd,
    const float* __restrict__ as, const float* __restrict__ ad,
    const float* __restrict__ bc, const int* __restrict__ found,
    float* __restrict__ out)
{
    const int p = blockIdx.x * 256 + threadIdx.x;
    if (p >= N_PAIRS) return;
    float v = as[ps[p]] + ad[pd[p]] + bc[0];
    float sg = 1.f / (1.f + __expf(-v));
    out[p] = found[p] ? sg : 0.f;
}

extern "C" void kernel_launch(void* const* d_in, const int* in_sizes, int n_in,
                              void* d_out, int out_size, void* d_ws, size_t ws_size,
                              hipStream_t stream)
{
    const float* feat = (const float*)d_in[0];
    const float* W1   = (const float*)d_in[1];
    const float* al1  = (const float*)d_in[2];
    const float* ar1  = (const float*)d_in[3];
    const float* W2   = (const float*)d_in[4];
    const float* al2  = (const float*)d_in[5];
    const float* ar2  = (const float*)d_in[6];
    const float* Wc   = (const float*)d_in[7];
    const float* bc   = (const float*)d_in[8];
    const int* src    = (const int*)d_in[9];
    const int* dst    = (const int*)d_in[10];
    const int* psrc   = (const int*)d_in[11];
    const int* pdst   = (const int*)d_in[12];
    float* out = (float*)d_out;

    char* ws = (char*)d_ws;
    unsigned short* z  = (unsigned short*)ws;  ws += (size_t)N_NODES * HID * 2;  // layer-1 z
    unsigned short* z2 = (unsigned short*)ws;  ws += (size_t)N_NODES * HID * 2;  // layer-2 z
    float* el = (float*)ws;               ws += (size_t)N_NODES * 4;
    float* er = (float*)ws;               ws += (size_t)N_NODES * 4;
    float* as = (float*)ws;               ws += (size_t)N_NODES * 4;
    float* ad = (float*)ws;               ws += (size_t)N_NODES * 4;
    float* el2 = (float*)ws;              ws += (size_t)N_NODES * 4;
    float* er2 = (float*)ws;              ws += (size_t)N_NODES * 4;
    int* row_start = (int*)ws;            ws += (size_t)(N_NODES + 1) * 4;
    int* histHi = (int*)ws;               ws += (size_t)MHIST * 4;
    int* bsumsA = (int*)ws;               ws += (size_t)(SBG + 1) * 4;
    int* found = (int*)ws;                ws += (size_t)N_PAIRS * 4;
    ws = (char*)(((uintptr_t)ws + 255) & ~(uintptr_t)255);
    unsigned* pairs = (unsigned*)ws;      ws += (size_t)N_EDGES * 4;
    unsigned short* csr_src = (unsigned short*)ws;  ws += (size_t)N_EDGES * 2;
    ws = (char*)(((uintptr_t)ws + 255) & ~(uintptr_t)255);
    unsigned short* w1hi = (unsigned short*)ws;  ws += 8192 * 2;
    unsigned short* w1lo = (unsigned short*)ws;  ws += 8192 * 2;
    unsigned short* w2hi = (unsigned short*)ws;  ws += 4096 * 2;
    unsigned short* w2lo = (unsigned short*)ws;  ws += 4096 * 2;

    dim3 b64x4(64, 4);

    // 1) bucket histogram (320-way) + W prep
    hist_prep<<<NCH + 32, 256, 0, stream>>>(dst, histHi, W1, W2, w1hi, w1lo, w2hi, w2lo);
    // 2) scan over MHIST (tiny)
    scan1g<<<SBG, 256, 0, stream>>>(histHi, bsumsA);
    // 3) bucket scatter (320-way) || layer-1 GEMM (fused: gemm hides behind scatter)
    scatter_gemm1<<<NCH + MB_GEMM, b64x4, 0, stream>>>(src, dst, histHi, bsumsA, pairs,
        feat, w1hi, w1lo, al1, ar1, z, el, er);
    // 4) segment sort (1024-thread blocks) -> row_start + csr_src (u16)
    seg_sort<<<NBIN, SEG_T, 0, stream>>>(pairs, histHi, bsumsA, row_start, csr_src);
    // 5) layer-1 aggregate (LDS) + layer-2 GEMM || pair membership
    agg1_gemm2_member<<<N_WAVES_GEMM + MEMBER_BLOCKS, b64x4, 0, stream>>>(
        row_start, csr_src, el, er, z, w2hi, w2lo, al2, ar2,
        z2, el2, er2, psrc, pdst, found);
    // 6) layer-2 aggregate + head dots
    agg2<<<NODE_BLOCKS, b64x4, 0, stream>>>(row_start, csr_src, el2, er2, z2, Wc, as, ad);
    // 7) final pair output
    pair_tiny<<<(N_PAIRS + 255) / 256, 256, 0, stream>>>(psrc, pdst, as, ad, bc, found, out);
}